// Round 3
// baseline (96.963 us; speedup 1.0000x reference)
//
#include <hip/hip_runtime.h>
#include <math.h>

#define BDIM 8
#define SDIM 2048
#define EDIM 512
#define LDIM 128
#define MTOT (BDIM * SDIM)   // 16384
#define TM 16                // rows per block; grid = 1024 blocks x 256 thr

typedef __attribute__((ext_vector_type(8))) short s8v;    // 8 bf16 MFMA frag
typedef __attribute__((ext_vector_type(4))) float f4v;

__device__ __forceinline__ unsigned short f2bf(float x) {
    union { float f; unsigned u; } c; c.f = x;
    return (unsigned short)((c.u + 0x7fffu + ((c.u >> 16) & 1u)) >> 16);  // RNE
}

// ---- prep: B in MFMA-fragment-linear bf16 layout, m2[l], inv_var, coef ----
// Fragment-linear: element (l, e) lives at
//   BF[((kt*8 + ct)*64 + kg*16 + fr)*8 + j],
//   kt=e/32, kg=(e/8)%4, j=e%8, ct=l/16, fr=l%16
// so a wave's B-fragment load for tile (kt,ct) is one coalesced 16B/lane read.
__global__ __launch_bounds__(64) void gs_prep(
    const float* __restrict__ means, const float* __restrict__ var,
    unsigned short* __restrict__ BF, float* __restrict__ m2,
    float* __restrict__ ivbuf, float* __restrict__ coef)
{
    const int l = blockIdx.x;    // 0..127
    const int t = threadIdx.x;   // 0..63
    const int e0 = t * 8;

    float mv[8], iv[8];
    const float* mrow = means + l * EDIM + e0;
#pragma unroll
    for (int i = 0; i < 8; ++i) { mv[i] = mrow[i]; iv[i] = 1.0f / var[e0 + i]; }

    float part = 0.0f;
    s8v pr;
#pragma unroll
    for (int i = 0; i < 8; ++i) {
        float p = mv[i] * iv[i];            // means * inv_var
        pr[i] = (short)f2bf(p);
        part += mv[i] * p;                  // means^2 * inv_var
    }
    const int ct = l >> 4, fr = l & 15;
    const int kt = t >> 2, kg = t & 3;      // e0 = kt*32 + kg*8
    *(s8v*)(BF + (((kt * 8 + ct) * 64) + kg * 16 + fr) * 8) = pr;

#pragma unroll
    for (int off = 32; off > 0; off >>= 1) part += __shfl_down(part, off, 64);
    if (t == 0) m2[l] = part;

    if (l == 0) {
#pragma unroll
        for (int i = 0; i < 8; ++i) ivbuf[e0 + i] = iv[i];
        float ld = 0.0f;
#pragma unroll
        for (int i = 0; i < 8; ++i) ld += logf(var[e0 + i]);
#pragma unroll
        for (int off = 32; off > 0; off >>= 1) ld += __shfl_down(ld, off, 64);
        if (t == 0) {
            const float factor = -(float)EDIM * 0.5f * 1.8378770664093453f; // ln(2*pi)
            *coef = factor - 0.5f * ld;
        }
    }
}

// ---- main: barrier-free, LDS-free. 1024 blocks x 256 thr.
// Each wave owns all 16 rows x 32 cols (2 ct tiles); waves split columns.
// A-fragments loaded directly from global as f32 (lane l -> row l&15,
// k=(l>>4)*8..+8), converted in-register; B-fragments from L2-resident BF.
// No __syncthreads in the k-loop -> no compiler-forced vmcnt(0) drain;
// the unrolled loop software-pipelines freely.
__global__ __launch_bounds__(256) void gs_main(
    const float* __restrict__ emb, const unsigned short* __restrict__ BF,
    const float* __restrict__ m2, const float* __restrict__ ivbuf,
    const float* __restrict__ coef, float* __restrict__ out)
{
    const int t    = threadIdx.x;
    const int lane = t & 63;
    const int wave = t >> 6;                 // cols wave*32 .. wave*32+31
    const int m0   = blockIdx.x * TM;

    const int fr = lane & 15;                // fragment row (A) / col (B,C)
    const int kg = lane >> 4;                // k-group 0..3

    const float* ap  = emb + (m0 + fr) * EDIM + kg * 8;   // A: own row, own k-slice
    const float* ivp = ivbuf + kg * 8;
    const unsigned short* bfp = BF + (wave * 2 * 64 + lane) * 8;  // ct=wave*2

    f4v acc0 = (f4v)0.0f, acc1 = (f4v)0.0f;
    float e2acc = 0.0f;

#pragma unroll 4
    for (int c = 0; c < 16; ++c) {           // 16 chunks of K=32
        f4v x0 = *(const f4v*)(ap + c * 32);
        f4v x1 = *(const f4v*)(ap + c * 32 + 4);
        f4v v0 = *(const f4v*)(ivp + c * 32);
        f4v v1 = *(const f4v*)(ivp + c * 32 + 4);
        s8v b0 = *(const s8v*)(bfp + c * 4096);          // kt stride = 4096 shorts
        s8v b1 = *(const s8v*)(bfp + c * 4096 + 512);    // ct+1 tile

        s8v a8;
#pragma unroll
        for (int i = 0; i < 4; ++i) {
            a8[i] = (short)f2bf(x0[i]);
            e2acc += x0[i] * x0[i] * v0[i];
        }
#pragma unroll
        for (int i = 0; i < 4; ++i) {
            a8[4 + i] = (short)f2bf(x1[i]);
            e2acc += x1[i] * x1[i] * v1[i];
        }
        acc0 = __builtin_amdgcn_mfma_f32_16x16x32_bf16(a8, b0, acc0, 0, 0, 0);
        acc1 = __builtin_amdgcn_mfma_f32_16x16x32_bf16(a8, b1, acc1, 0, 0, 0);
    }

    // e2: lane holds partial for (row=fr, k-slices of kg). Sum across kg groups.
    e2acc += __shfl_xor(e2acc, 16, 64);
    e2acc += __shfl_xor(e2acc, 32, 64);      // now every lane: e2[fr] complete

    const float cf  = *coef;
    const int   n0  = wave * 32 + fr;
    const float cm0 = cf - 0.5f * m2[n0];
    const float cm1 = cf - 0.5f * m2[n0 + 16];
    float* orow = out + m0 * LDIM;
#pragma unroll
    for (int r = 0; r < 4; ++r) {
        const int row = kg * 4 + r;          // C/D: col=lane&15, row=quad*4+reg
        const float eh = 0.5f * __shfl(e2acc, row, 64);  // e2[row] from lane 'row'
        orow[row * LDIM + n0]      = acc0[r] + cm0 - eh;
        orow[row * LDIM + n0 + 16] = acc1[r] + cm1 - eh;
    }
}

extern "C" void kernel_launch(void* const* d_in, const int* in_sizes, int n_in,
                              void* d_out, int out_size, void* d_ws, size_t ws_size,
                              hipStream_t stream) {
    const float* emb   = (const float*)d_in[0];
    const float* means = (const float*)d_in[1];
    const float* var   = (const float*)d_in[2];
    float* out = (float*)d_out;

    char* ws = (char*)d_ws;
    unsigned short* BF = (unsigned short*)ws;            // 131072 B frag-linear B
    float* m2    = (float*)(ws + 131072);                // 512 B
    float* ivbuf = (float*)(ws + 131584);                // 2048 B
    float* coef  = (float*)(ws + 133632);                // 4 B

    gs_prep<<<LDIM, 64, 0, stream>>>(means, var, BF, m2, ivbuf, coef);
    gs_main<<<MTOT / TM, 256, 0, stream>>>(emb, BF, m2, ivbuf, coef, out);
}

// Round 4
// 82.587 us; speedup vs baseline: 1.1741x; 1.1741x over previous
//
#include <hip/hip_runtime.h>
#include <math.h>

#define BDIM 8
#define SDIM 2048
#define EDIM 512
#define LDIM 128
#define MTOT (BDIM * SDIM)   // 16384
#define TM 16                // rows per block (16 rows x 128 cols per block)
#define BK 64                // k-chunk
#define NCH (EDIM / BK)      // 8 chunks
#define LSTR 72              // shorts per LDS row (144 B stride, 16B-aligned)

typedef __attribute__((ext_vector_type(8))) short s8v;    // 8 bf16 MFMA frag
typedef __attribute__((ext_vector_type(4))) short s4v;    // 4 bf16
typedef __attribute__((ext_vector_type(4))) float f4v;

__device__ __forceinline__ unsigned short f2bf(float x) {
    union { float f; unsigned u; } c; c.f = x;
    return (unsigned short)((c.u + 0x7fffu + ((c.u >> 16) & 1u)) >> 16);  // RNE
}

// ---- prep: B in MFMA-fragment-linear bf16 layout, m2[l], inv_var, coef ----
// Fragment-linear: element (l, e) lives at
//   BF[((kt*8 + ct)*64 + kg*16 + fr)*8 + j],
//   kt=e/32, kg=(e/8)%4, j=e%8, ct=l/16, fr=l%16
// so a wave's B-fragment load for tile (kt,ct) is one coalesced 16B/lane read.
__global__ __launch_bounds__(64) void gs_prep(
    const float* __restrict__ means, const float* __restrict__ var,
    unsigned short* __restrict__ BF, float* __restrict__ m2,
    float* __restrict__ ivbuf, float* __restrict__ coef)
{
    const int l = blockIdx.x;    // 0..127
    const int t = threadIdx.x;   // 0..63
    const int e0 = t * 8;

    float mv[8], iv[8];
    const float* mrow = means + l * EDIM + e0;
#pragma unroll
    for (int i = 0; i < 8; ++i) { mv[i] = mrow[i]; iv[i] = 1.0f / var[e0 + i]; }

    float part = 0.0f;
    s8v pr;
#pragma unroll
    for (int i = 0; i < 8; ++i) {
        float p = mv[i] * iv[i];            // means * inv_var
        pr[i] = (short)f2bf(p);
        part += mv[i] * p;                  // means^2 * inv_var
    }
    const int ct = l >> 4, fr = l & 15;
    const int kt = t >> 2, kg = t & 3;      // e0 = kt*32 + kg*8
    *(s8v*)(BF + (((kt * 8 + ct) * 64) + kg * 16 + fr) * 8) = pr;

#pragma unroll
    for (int off = 32; off > 0; off >>= 1) part += __shfl_down(part, off, 64);
    if (t == 0) m2[l] = part;

    if (l == 0) {
#pragma unroll
        for (int i = 0; i < 8; ++i) ivbuf[e0 + i] = iv[i];
        float ld = 0.0f;
#pragma unroll
        for (int i = 0; i < 8; ++i) ld += logf(var[e0 + i]);
#pragma unroll
        for (int off = 32; off > 0; off >>= 1) ld += __shfl_down(ld, off, 64);
        if (t == 0) {
            const float factor = -(float)EDIM * 0.5f * 1.8378770664093453f; // ln(2*pi)
            *coef = factor - 0.5f * ld;
        }
    }
}

// ---- main: M=16384 x N=128 x K=512 streaming bf16 MFMA + rank-1 corrections.
// 1024 blocks x 256 thr (16 waves/CU). A: reg-prefetch -> dbuf LDS, 1 barrier
// per chunk. B: fragment loads straight from L2 (no LDS). e2 fused into convert.
__global__ __launch_bounds__(256) void gs_main(
    const float* __restrict__ emb, const unsigned short* __restrict__ BF,
    const float* __restrict__ m2, const float* __restrict__ ivbuf,
    const float* __restrict__ coef, float* __restrict__ out)
{
    __shared__ __align__(16) unsigned short Alds[2][TM][LSTR];  // 2x16x72 shorts
    __shared__ float e2s[TM];

    const int t    = threadIdx.x;
    const int lane = t & 63;
    const int wave = t >> 6;                 // 0..3 -> cols wave*32..wave*32+31
    const int m0   = blockIdx.x * TM;

    // staging map: thread covers (arow, kq..kq+3) of each 16x64 chunk
    const int arow = t >> 4;                 // 0..15
    const int kq   = (t & 15) * 4;           // 0..60

    // fragment map
    const int fr = lane & 15;
    const int kg = lane >> 4;

    const float* embp = emb + (m0 + arow) * EDIM + kq;
    // B frag base for (kt=0, ct=wave*2): tile stride 512 shorts in ct, 4096 in kt
    const unsigned short* bfp = BF + (wave * 2 * 64 + lane) * 8;

    f4v acc0 = (f4v)0.0f, acc1 = (f4v)0.0f;
    float e2acc = 0.0f;

    // prologue: chunk 0 in flight
    f4v a_cur  = *(const f4v*)(embp);
    f4v iv_cur = *(const f4v*)(ivbuf + kq);
    s8v b00 = *(const s8v*)(bfp);
    s8v b01 = *(const s8v*)(bfp + 512);
    s8v b10 = *(const s8v*)(bfp + 4096);
    s8v b11 = *(const s8v*)(bfp + 4608);

#pragma unroll
    for (int kc = 0; kc < NCH; ++kc) {
        // convert + fused e2, write A chunk to LDS buffer kc&1
        s4v a4;
#pragma unroll
        for (int i = 0; i < 4; ++i) {
            a4[i] = (short)f2bf(a_cur[i]);
            e2acc += a_cur[i] * a_cur[i] * iv_cur[i];
        }
        *(s4v*)&Alds[kc & 1][arow][kq] = a4;

        // issue next chunk's loads; they stay in flight across barrier+MFMA
        f4v a_nxt, iv_nxt;
        s8v nb00, nb01, nb10, nb11;
        if (kc + 1 < NCH) {
            a_nxt  = *(const f4v*)(embp + (kc + 1) * BK);
            iv_nxt = *(const f4v*)(ivbuf + (kc + 1) * BK + kq);
            const unsigned short* bp = bfp + (kc + 1) * 8192;  // kt += 2
            nb00 = *(const s8v*)(bp);
            nb01 = *(const s8v*)(bp + 512);
            nb10 = *(const s8v*)(bp + 4096);
            nb11 = *(const s8v*)(bp + 4608);
        }
        __syncthreads();   // single barrier per chunk (dbuf makes it sufficient)

        s8v af0 = *(const s8v*)&Alds[kc & 1][fr][kg * 8];        // ks=0..31
        s8v af1 = *(const s8v*)&Alds[kc & 1][fr][32 + kg * 8];   // ks=32..63
        acc0 = __builtin_amdgcn_mfma_f32_16x16x32_bf16(af0, b00, acc0, 0, 0, 0);
        acc1 = __builtin_amdgcn_mfma_f32_16x16x32_bf16(af0, b01, acc1, 0, 0, 0);
        acc0 = __builtin_amdgcn_mfma_f32_16x16x32_bf16(af1, b10, acc0, 0, 0, 0);
        acc1 = __builtin_amdgcn_mfma_f32_16x16x32_bf16(af1, b11, acc1, 0, 0, 0);

        if (kc + 1 < NCH) {
            a_cur = a_nxt; iv_cur = iv_nxt;
            b00 = nb00; b01 = nb01; b10 = nb10; b11 = nb11;
        }
    }

    // e2 row sums: row r's partials live in the 16 consecutive lanes 16r..16r+15
#pragma unroll
    for (int off = 8; off > 0; off >>= 1) e2acc += __shfl_down(e2acc, off, 16);
    if ((t & 15) == 0) e2s[arow] = e2acc;
    __syncthreads();

    const float cf  = *coef;
    const int   n0  = wave * 32 + fr;
    const float cm0 = cf - 0.5f * m2[n0];
    const float cm1 = cf - 0.5f * m2[n0 + 16];
    float* orow = out + m0 * LDIM;
#pragma unroll
    for (int r = 0; r < 4; ++r) {
        const int row = kg * 4 + r;          // C/D: col=lane&15, row=quad*4+reg
        const float eh = 0.5f * e2s[row];
        orow[row * LDIM + n0]      = acc0[r] + cm0 - eh;
        orow[row * LDIM + n0 + 16] = acc1[r] + cm1 - eh;
    }
}

extern "C" void kernel_launch(void* const* d_in, const int* in_sizes, int n_in,
                              void* d_out, int out_size, void* d_ws, size_t ws_size,
                              hipStream_t stream) {
    const float* emb   = (const float*)d_in[0];
    const float* means = (const float*)d_in[1];
    const float* var   = (const float*)d_in[2];
    float* out = (float*)d_out;

    char* ws = (char*)d_ws;
    unsigned short* BF = (unsigned short*)ws;            // 131072 B frag-linear B
    float* m2    = (float*)(ws + 131072);                // 512 B
    float* ivbuf = (float*)(ws + 131584);                // 2048 B
    float* coef  = (float*)(ws + 133632);                // 4 B

    gs_prep<<<LDIM, 64, 0, stream>>>(means, var, BF, m2, ivbuf, coef);
    gs_main<<<MTOT / TM, 256, 0, stream>>>(emb, BF, m2, ivbuf, coef, out);
}